// Round 7
// baseline (260.370 us; speedup 1.0000x reference)
//
#include <hip/hip_runtime.h>
#include <hip/hip_bf16.h>
#include <math.h>

#define N_NODES 50000
#define N_EDGES 500000
#define H_DIM   128
#define BN_EPS  1e-5f
#define GEMM_GRID ((N_NODES + 31) / 32)     // 1563: one 32-row tile per block
#define SCAN_NBLK ((N_NODES + 255) / 256)   // 196

// ---------------------------------------------------------------------------
// K1: histogram of dst -> deg[]
// ---------------------------------------------------------------------------
__global__ __launch_bounds__(256) void hist_kernel(
    const int* __restrict__ dst, int* __restrict__ deg)
{
    int e = blockIdx.x * blockDim.x + threadIdx.x;
    if (e < N_EDGES) atomicAdd(&deg[dst[e]], 1);
}

// ---------------------------------------------------------------------------
// K2a: per-block sums of deg (196 blocks x 256)
// ---------------------------------------------------------------------------
__global__ __launch_bounds__(256) void scan_partial_kernel(
    const int* __restrict__ deg, int* __restrict__ blocksum)
{
    __shared__ int red[256];
    int t = threadIdx.x;
    int i = blockIdx.x * 256 + t;
    red[t] = (i < N_NODES) ? deg[i] : 0;
    __syncthreads();
    #pragma unroll
    for (int off = 128; off; off >>= 1) {
        if (t < off) red[t] += red[t + off];
        __syncthreads();
    }
    if (t == 0) blocksum[blockIdx.x] = red[0];
}

// ---------------------------------------------------------------------------
// K2b: exclusive scan of the 196 block sums (one 256-thread block)
// ---------------------------------------------------------------------------
__global__ __launch_bounds__(256) void scan_blocksums_kernel(
    const int* __restrict__ blocksum, int* __restrict__ blockoff)
{
    __shared__ int s[256];
    int t = threadIdx.x;
    s[t] = (t < SCAN_NBLK) ? blocksum[t] : 0;
    __syncthreads();
    for (int off = 1; off < 256; off <<= 1) {
        int v = (t >= off) ? s[t - off] : 0;
        __syncthreads();
        s[t] += v;
        __syncthreads();
    }
    if (t < SCAN_NBLK) blockoff[t] = (t == 0) ? 0 : s[t - 1];
}

// ---------------------------------------------------------------------------
// K2c: in-block exclusive scan + block offset -> rowptr, cursor
// ---------------------------------------------------------------------------
__global__ __launch_bounds__(256) void scan_final_kernel(
    const int* __restrict__ deg, const int* __restrict__ blockoff,
    int* __restrict__ rowptr, int* __restrict__ cursor)
{
    __shared__ int s[256];
    int t = threadIdx.x;
    int i = blockIdx.x * 256 + t;
    int v = (i < N_NODES) ? deg[i] : 0;
    s[t] = v;
    __syncthreads();
    for (int off = 1; off < 256; off <<= 1) {
        int u = (t >= off) ? s[t - off] : 0;
        __syncthreads();
        s[t] += u;
        __syncthreads();
    }
    int excl = s[t] - v + blockoff[blockIdx.x];
    if (i < N_NODES) {
        rowptr[i] = excl;
        cursor[i] = excl;
        if (i == N_NODES - 1) rowptr[N_NODES] = excl + v;
    }
}

// ---------------------------------------------------------------------------
// K3: scatter src ids into CSR slots (counting sort by dst)
// ---------------------------------------------------------------------------
__global__ __launch_bounds__(256) void csr_scatter_kernel(
    const int* __restrict__ src, const int* __restrict__ dst,
    int* __restrict__ cursor, int* __restrict__ csr_src)
{
    int e = blockIdx.x * blockDim.x + threadIdx.x;
    if (e >= N_EDGES) return;
    int pos = atomicAdd(&cursor[dst[e]], 1);
    csr_src[pos] = src[e];
}

// ---------------------------------------------------------------------------
// K4: per-dst-node fused dot + online softmax + weighted aggregate.
// 32 lanes per node, 4-way edge unroll, zero atomics, one store per lane.
// ---------------------------------------------------------------------------
__global__ __launch_bounds__(256) void node_aggregate_kernel(
    const float* __restrict__ emb,
    const int* __restrict__ rowptr,
    const int* __restrict__ csr_src,
    float* __restrict__ neigh)
{
    int node = blockIdx.x * 8 + (threadIdx.x >> 5);
    int lane = threadIdx.x & 31;
    if (node >= N_NODES) return;

    int beg = rowptr[node];
    int end = rowptr[node + 1];

    const float4 b = *((const float4*)(emb + (size_t)node * H_DIM) + lane);

    float m = -INFINITY;
    float denom = 0.f;
    float4 acc = {0.f, 0.f, 0.f, 0.f};

    int e = beg;
    for (; e + 4 <= end; e += 4) {
        int s0 = csr_src[e + 0];
        int s1 = csr_src[e + 1];
        int s2 = csr_src[e + 2];
        int s3 = csr_src[e + 3];
        float4 a0 = *((const float4*)(emb + (size_t)s0 * H_DIM) + lane);
        float4 a1 = *((const float4*)(emb + (size_t)s1 * H_DIM) + lane);
        float4 a2 = *((const float4*)(emb + (size_t)s2 * H_DIM) + lane);
        float4 a3 = *((const float4*)(emb + (size_t)s3 * H_DIM) + lane);
        float p0 = a0.x * b.x + a0.y * b.y + a0.z * b.z + a0.w * b.w;
        float p1 = a1.x * b.x + a1.y * b.y + a1.z * b.z + a1.w * b.w;
        float p2 = a2.x * b.x + a2.y * b.y + a2.z * b.z + a2.w * b.w;
        float p3 = a3.x * b.x + a3.y * b.y + a3.z * b.z + a3.w * b.w;
        #pragma unroll
        for (int off = 16; off; off >>= 1) {
            p0 += __shfl_xor(p0, off);
            p1 += __shfl_xor(p1, off);
            p2 += __shfl_xor(p2, off);
            p3 += __shfl_xor(p3, off);
        }
        float mn = fmaxf(fmaxf(fmaxf(p0, p1), fmaxf(p2, p3)), m);
        float corr = __expf(m - mn);          // first iter: exp(-inf)=0
        float w0 = __expf(p0 - mn);
        float w1 = __expf(p1 - mn);
        float w2 = __expf(p2 - mn);
        float w3 = __expf(p3 - mn);
        denom = denom * corr + w0 + w1 + w2 + w3;
        acc.x = acc.x * corr + a0.x * w0 + a1.x * w1 + a2.x * w2 + a3.x * w3;
        acc.y = acc.y * corr + a0.y * w0 + a1.y * w1 + a2.y * w2 + a3.y * w3;
        acc.z = acc.z * corr + a0.z * w0 + a1.z * w1 + a2.z * w2 + a3.z * w3;
        acc.w = acc.w * corr + a0.w * w0 + a1.w * w1 + a2.w * w2 + a3.w * w3;
        m = mn;
    }
    for (; e < end; ++e) {
        int s = csr_src[e];
        float4 a = *((const float4*)(emb + (size_t)s * H_DIM) + lane);
        float p = a.x * b.x + a.y * b.y + a.z * b.z + a.w * b.w;
        #pragma unroll
        for (int off = 16; off; off >>= 1)
            p += __shfl_xor(p, off);
        float mn   = fmaxf(m, p);
        float corr = __expf(m - mn);
        float w    = __expf(p - mn);
        denom = denom * corr + w;
        acc.x = acc.x * corr + a.x * w;
        acc.y = acc.y * corr + a.y * w;
        acc.z = acc.z * corr + a.z * w;
        acc.w = acc.w * corr + a.w * w;
        m = mn;
    }

    float inv = (end > beg) ? (1.0f / denom) : 0.f;
    float4 o = {acc.x * inv, acc.y * inv, acc.z * inv, acc.w * inv};
    *((float4*)(neigh + (size_t)node * H_DIM) + lane) = o;
}

// ---------------------------------------------------------------------------
// K5: h = neigh @ W (fp32), one 32-row tile per block, k-sliced W staging.
// LDS = Ws[32][128] + As[32][128] = 32 KB -> 5 blocks/CU (20 waves, was 2/8).
// W re-staged per block (~100 MB aggregate L2 reads ~ 3 us, cheap).
// Column sum/sumsq partials via block LDS reduce + one plain store/thread.
// ---------------------------------------------------------------------------
__global__ __launch_bounds__(256) void gemm_stats_kernel(
    const float* __restrict__ neigh,
    const float* __restrict__ W,
    float* __restrict__ h,
    float* __restrict__ partial)
{
    __shared__ float Ws[32][128];    // 16 KB: one k-slice of W
    __shared__ float As[32][128];    // 16 KB: 32-row tile (reused for reduce)

    int t  = threadIdx.x;
    int tx = t & 31;
    int ty = t >> 5;
    int r0 = blockIdx.x * 32;

    // stage 32 rows of neigh (float4, coalesced)
    const float4 z4 = {0.f, 0.f, 0.f, 0.f};
    for (int i = t; i < 32 * 32; i += 256) {
        int r = i >> 5, c4 = i & 31;
        int gr = r0 + r;
        float4 v = (gr < N_NODES) ? ((const float4*)(neigh + (size_t)gr * H_DIM))[c4] : z4;
        *(float4*)(&As[r][c4 * 4]) = v;
    }

    float acc[4][4];
    #pragma unroll
    for (int i = 0; i < 4; ++i)
        #pragma unroll
        for (int j = 0; j < 4; ++j)
            acc[i][j] = 0.f;

    for (int ks = 0; ks < 4; ++ks) {
        __syncthreads();             // As staged (ks=0) / prev slice consumed
        for (int i = t; i < 32 * 32; i += 256) {
            int kk = i >> 5, c4 = i & 31;
            *(float4*)(&Ws[kk][c4 * 4]) =
                ((const float4*)(W + (size_t)(ks * 32 + kk) * H_DIM))[c4];
        }
        __syncthreads();

        #pragma unroll 8
        for (int kk = 0; kk < 32; ++kk) {
            float4 w = *(const float4*)(&Ws[kk][tx * 4]);
            int k = ks * 32 + kk;
            #pragma unroll
            for (int i = 0; i < 4; ++i) {
                float a = As[ty * 4 + i][k];
                acc[i][0] += a * w.x;
                acc[i][1] += a * w.y;
                acc[i][2] += a * w.z;
                acc[i][3] += a * w.w;
            }
        }
    }

    float csum[4] = {0.f, 0.f, 0.f, 0.f};
    float csq[4]  = {0.f, 0.f, 0.f, 0.f};

    #pragma unroll
    for (int i = 0; i < 4; ++i) {
        int gr = r0 + ty * 4 + i;
        if (gr < N_NODES) {
            float4 out;
            out.x = acc[i][0]; out.y = acc[i][1];
            out.z = acc[i][2]; out.w = acc[i][3];
            *(float4*)(h + (size_t)gr * H_DIM + tx * 4) = out;
            #pragma unroll
            for (int j = 0; j < 4; ++j) {
                csum[j] += acc[i][j];
                csq[j]  += acc[i][j] * acc[i][j];
            }
        }
    }

    // block-level reduction across ty (stride-9 pad), one plain store/thread
    __syncthreads();
    float* red = &As[0][0];          // needs 256*9 = 2304 floats, 4096 avail
    #pragma unroll
    for (int j = 0; j < 4; ++j) {
        red[(tx * 8 + j) * 9 + ty]     = csum[j];
        red[(tx * 8 + 4 + j) * 9 + ty] = csq[j];
    }
    __syncthreads();
    float s = 0.f;
    #pragma unroll
    for (int q = 0; q < 8; ++q)
        s += red[t * 9 + q];
    partial[(size_t)blockIdx.x * 256 + t] = s;
}

// ---------------------------------------------------------------------------
// K6: sum 1563 partials per value (4-way split, 1024 thr), fold BN stats.
// ---------------------------------------------------------------------------
__global__ __launch_bounds__(1024) void bn_stats_kernel(
    const float* __restrict__ partial,
    const float* __restrict__ gamma,
    const float* __restrict__ beta,
    float* __restrict__ scale,
    float* __restrict__ shift)
{
    __shared__ float tot[4][256];
    __shared__ float tot2[256];
    int v = threadIdx.x & 255;
    int q = threadIdx.x >> 8;
    float s = 0.f;
    for (int b = q; b < GEMM_GRID; b += 4)
        s += partial[(size_t)b * 256 + v];     // coalesced, L2-resident
    tot[q][v] = s;
    __syncthreads();
    if (threadIdx.x < 256)
        tot2[v] = tot[0][v] + tot[1][v] + tot[2][v] + tot[3][v];
    __syncthreads();
    if (threadIdx.x < 128) {
        int c = threadIdx.x;
        int base = (c >> 2) * 8 + (c & 3);
        float cs = tot2[base];
        float cq = tot2[base + 4];
        const float invN = 1.0f / (float)N_NODES;
        float mu  = cs * invN;
        float var = cq * invN - mu * mu;       // biased, matches jnp.var
        float sc  = gamma[c] * rsqrtf(var + BN_EPS);
        scale[c] = sc;
        shift[c] = beta[c] - mu * sc;
    }
}

// ---------------------------------------------------------------------------
// K7: out = tanh(h*scale + shift), in place
// ---------------------------------------------------------------------------
__global__ __launch_bounds__(256) void bn_tanh_kernel(
    float* __restrict__ h,
    const float* __restrict__ scale,
    const float* __restrict__ shift)
{
    size_t i = (size_t)blockIdx.x * blockDim.x + threadIdx.x;
    size_t idx4 = i * 4;
    if (idx4 >= (size_t)N_NODES * H_DIM) return;
    int c = (int)(idx4 & (H_DIM - 1));
    float4 v = *(float4*)(h + idx4);
    v.x = tanhf(v.x * scale[c + 0] + shift[c + 0]);
    v.y = tanhf(v.y * scale[c + 1] + shift[c + 1]);
    v.z = tanhf(v.z * scale[c + 2] + shift[c + 2]);
    v.w = tanhf(v.w * scale[c + 3] + shift[c + 3]);
    *(float4*)(h + idx4) = v;
}

// ---------------------------------------------------------------------------
extern "C" void kernel_launch(void* const* d_in, const int* in_sizes, int n_in,
                              void* d_out, int out_size, void* d_ws, size_t ws_size,
                              hipStream_t stream)
{
    const float* ent_emb = (const float*)d_in[0];
    const float* neigh_w = (const float*)d_in[1];
    const float* gamma   = (const float*)d_in[2];
    const float* beta    = (const float*)d_in[3];
    const int*   src     = (const int*)d_in[4];
    const int*   dst     = (const int*)d_in[5];
    float* out = (float*)d_out;

    char* ws = (char*)d_ws;
    float* neigh    = (float*)ws;                                    // 25.6 MB
    int*   deg      = (int*)(ws + (size_t)N_NODES * H_DIM * 4);      // 50000
    int*   rowptr   = deg + N_NODES;                                 // 50001
    int*   cursor   = rowptr + N_NODES + 1;                          // 50000
    int*   csr_src  = cursor + N_NODES;                              // 500000
    int*   blocksum = csr_src + N_EDGES;                             // 196
    int*   blockoff = blocksum + SCAN_NBLK;                          // 196
    float* partial  = (float*)(blockoff + SCAN_NBLK);                // 1563*256
    float* scale    = partial + (size_t)GEMM_GRID * 256;
    float* shift    = scale + H_DIM;

    hipMemsetAsync(deg, 0, N_NODES * sizeof(int), stream);

    // CSR build (counting sort by dst); hierarchical 3-kernel scan
    hist_kernel<<<(N_EDGES + 255) / 256, 256, 0, stream>>>(dst, deg);
    scan_partial_kernel<<<SCAN_NBLK, 256, 0, stream>>>(deg, blocksum);
    scan_blocksums_kernel<<<1, 256, 0, stream>>>(blocksum, blockoff);
    scan_final_kernel<<<SCAN_NBLK, 256, 0, stream>>>(deg, blockoff, rowptr, cursor);
    csr_scatter_kernel<<<(N_EDGES + 255) / 256, 256, 0, stream>>>(src, dst, cursor, csr_src);

    // fused dot + online softmax + aggregate (one store per lane, no atomics)
    node_aggregate_kernel<<<(N_NODES + 7) / 8, 256, 0, stream>>>(
        ent_emb, rowptr, csr_src, neigh);

    // h = neigh @ W + column partials, then BN + tanh
    gemm_stats_kernel<<<GEMM_GRID, 256, 0, stream>>>(neigh, neigh_w, out, partial);
    bn_stats_kernel<<<1, 1024, 0, stream>>>(partial, gamma, beta, scale, shift);
    {
        size_t total4 = (size_t)N_NODES * H_DIM / 4;
        int blocks = (int)((total4 + 255) / 256);
        bn_tanh_kernel<<<blocks, 256, 0, stream>>>(out, scale, shift);
    }
}

// Round 8
// 172.796 us; speedup vs baseline: 1.5068x; 1.5068x over previous
//
#include <hip/hip_runtime.h>
#include <hip/hip_bf16.h>
#include <math.h>

#define N_NODES 50000
#define N_EDGES 500000
#define H_DIM   128
#define BN_EPS  1e-5f
#define GEMM_GRID ((N_NODES + 31) / 32)     // 1563: one 32-row tile per block
#define SCAN_NBLK ((N_NODES + 255) / 256)   // 196
#define RED_NBLK  64                        // stage-1 partial-reduction blocks

// ---------------------------------------------------------------------------
// K1: histogram of dst -> deg[]
// ---------------------------------------------------------------------------
__global__ __launch_bounds__(256) void hist_kernel(
    const int* __restrict__ dst, int* __restrict__ deg)
{
    int e = blockIdx.x * blockDim.x + threadIdx.x;
    if (e < N_EDGES) atomicAdd(&deg[dst[e]], 1);
}

// ---------------------------------------------------------------------------
// K2a: per-block sums of deg (196 blocks x 256)
// ---------------------------------------------------------------------------
__global__ __launch_bounds__(256) void scan_partial_kernel(
    const int* __restrict__ deg, int* __restrict__ blocksum)
{
    __shared__ int red[256];
    int t = threadIdx.x;
    int i = blockIdx.x * 256 + t;
    red[t] = (i < N_NODES) ? deg[i] : 0;
    __syncthreads();
    #pragma unroll
    for (int off = 128; off; off >>= 1) {
        if (t < off) red[t] += red[t + off];
        __syncthreads();
    }
    if (t == 0) blocksum[blockIdx.x] = red[0];
}

// ---------------------------------------------------------------------------
// K2b: exclusive scan of the 196 block sums (one 256-thread block)
// ---------------------------------------------------------------------------
__global__ __launch_bounds__(256) void scan_blocksums_kernel(
    const int* __restrict__ blocksum, int* __restrict__ blockoff)
{
    __shared__ int s[256];
    int t = threadIdx.x;
    s[t] = (t < SCAN_NBLK) ? blocksum[t] : 0;
    __syncthreads();
    for (int off = 1; off < 256; off <<= 1) {
        int v = (t >= off) ? s[t - off] : 0;
        __syncthreads();
        s[t] += v;
        __syncthreads();
    }
    if (t < SCAN_NBLK) blockoff[t] = (t == 0) ? 0 : s[t - 1];
}

// ---------------------------------------------------------------------------
// K2c: in-block exclusive scan + block offset -> rowptr, cursor
// ---------------------------------------------------------------------------
__global__ __launch_bounds__(256) void scan_final_kernel(
    const int* __restrict__ deg, const int* __restrict__ blockoff,
    int* __restrict__ rowptr, int* __restrict__ cursor)
{
    __shared__ int s[256];
    int t = threadIdx.x;
    int i = blockIdx.x * 256 + t;
    int v = (i < N_NODES) ? deg[i] : 0;
    s[t] = v;
    __syncthreads();
    for (int off = 1; off < 256; off <<= 1) {
        int u = (t >= off) ? s[t - off] : 0;
        __syncthreads();
        s[t] += u;
        __syncthreads();
    }
    int excl = s[t] - v + blockoff[blockIdx.x];
    if (i < N_NODES) {
        rowptr[i] = excl;
        cursor[i] = excl;
        if (i == N_NODES - 1) rowptr[N_NODES] = excl + v;
    }
}

// ---------------------------------------------------------------------------
// K3: scatter src ids into CSR slots (counting sort by dst)
// ---------------------------------------------------------------------------
__global__ __launch_bounds__(256) void csr_scatter_kernel(
    const int* __restrict__ src, const int* __restrict__ dst,
    int* __restrict__ cursor, int* __restrict__ csr_src)
{
    int e = blockIdx.x * blockDim.x + threadIdx.x;
    if (e >= N_EDGES) return;
    int pos = atomicAdd(&cursor[dst[e]], 1);
    csr_src[pos] = src[e];
}

// ---------------------------------------------------------------------------
// K4: per-dst-node fused dot + online softmax + weighted aggregate.
// 32 lanes per node, 4-way edge unroll, zero atomics, one store per lane.
// ---------------------------------------------------------------------------
__global__ __launch_bounds__(256) void node_aggregate_kernel(
    const float* __restrict__ emb,
    const int* __restrict__ rowptr,
    const int* __restrict__ csr_src,
    float* __restrict__ neigh)
{
    int node = blockIdx.x * 8 + (threadIdx.x >> 5);
    int lane = threadIdx.x & 31;
    if (node >= N_NODES) return;

    int beg = rowptr[node];
    int end = rowptr[node + 1];

    const float4 b = *((const float4*)(emb + (size_t)node * H_DIM) + lane);

    float m = -INFINITY;
    float denom = 0.f;
    float4 acc = {0.f, 0.f, 0.f, 0.f};

    int e = beg;
    for (; e + 4 <= end; e += 4) {
        int s0 = csr_src[e + 0];
        int s1 = csr_src[e + 1];
        int s2 = csr_src[e + 2];
        int s3 = csr_src[e + 3];
        float4 a0 = *((const float4*)(emb + (size_t)s0 * H_DIM) + lane);
        float4 a1 = *((const float4*)(emb + (size_t)s1 * H_DIM) + lane);
        float4 a2 = *((const float4*)(emb + (size_t)s2 * H_DIM) + lane);
        float4 a3 = *((const float4*)(emb + (size_t)s3 * H_DIM) + lane);
        float p0 = a0.x * b.x + a0.y * b.y + a0.z * b.z + a0.w * b.w;
        float p1 = a1.x * b.x + a1.y * b.y + a1.z * b.z + a1.w * b.w;
        float p2 = a2.x * b.x + a2.y * b.y + a2.z * b.z + a2.w * b.w;
        float p3 = a3.x * b.x + a3.y * b.y + a3.z * b.z + a3.w * b.w;
        #pragma unroll
        for (int off = 16; off; off >>= 1) {
            p0 += __shfl_xor(p0, off);
            p1 += __shfl_xor(p1, off);
            p2 += __shfl_xor(p2, off);
            p3 += __shfl_xor(p3, off);
        }
        float mn = fmaxf(fmaxf(fmaxf(p0, p1), fmaxf(p2, p3)), m);
        float corr = __expf(m - mn);          // first iter: exp(-inf)=0
        float w0 = __expf(p0 - mn);
        float w1 = __expf(p1 - mn);
        float w2 = __expf(p2 - mn);
        float w3 = __expf(p3 - mn);
        denom = denom * corr + w0 + w1 + w2 + w3;
        acc.x = acc.x * corr + a0.x * w0 + a1.x * w1 + a2.x * w2 + a3.x * w3;
        acc.y = acc.y * corr + a0.y * w0 + a1.y * w1 + a2.y * w2 + a3.y * w3;
        acc.z = acc.z * corr + a0.z * w0 + a1.z * w1 + a2.z * w2 + a3.z * w3;
        acc.w = acc.w * corr + a0.w * w0 + a1.w * w1 + a2.w * w2 + a3.w * w3;
        m = mn;
    }
    for (; e < end; ++e) {
        int s = csr_src[e];
        float4 a = *((const float4*)(emb + (size_t)s * H_DIM) + lane);
        float p = a.x * b.x + a.y * b.y + a.z * b.z + a.w * b.w;
        #pragma unroll
        for (int off = 16; off; off >>= 1)
            p += __shfl_xor(p, off);
        float mn   = fmaxf(m, p);
        float corr = __expf(m - mn);
        float w    = __expf(p - mn);
        denom = denom * corr + w;
        acc.x = acc.x * corr + a.x * w;
        acc.y = acc.y * corr + a.y * w;
        acc.z = acc.z * corr + a.z * w;
        acc.w = acc.w * corr + a.w * w;
        m = mn;
    }

    float inv = (end > beg) ? (1.0f / denom) : 0.f;
    float4 o = {acc.x * inv, acc.y * inv, acc.z * inv, acc.w * inv};
    *((float4*)(neigh + (size_t)node * H_DIM) + lane) = o;
}

// ---------------------------------------------------------------------------
// K5: h = neigh @ W (fp32), one 32-row tile per block, k-sliced W staging.
// LDS = 32 KB -> 5 blocks/CU. Column partials -> partial[block][256].
// ---------------------------------------------------------------------------
__global__ __launch_bounds__(256) void gemm_stats_kernel(
    const float* __restrict__ neigh,
    const float* __restrict__ W,
    float* __restrict__ h,
    float* __restrict__ partial)
{
    __shared__ float Ws[32][128];    // 16 KB: one k-slice of W
    __shared__ float As[32][128];    // 16 KB: 32-row tile (reused for reduce)

    int t  = threadIdx.x;
    int tx = t & 31;
    int ty = t >> 5;
    int r0 = blockIdx.x * 32;

    const float4 z4 = {0.f, 0.f, 0.f, 0.f};
    for (int i = t; i < 32 * 32; i += 256) {
        int r = i >> 5, c4 = i & 31;
        int gr = r0 + r;
        float4 v = (gr < N_NODES) ? ((const float4*)(neigh + (size_t)gr * H_DIM))[c4] : z4;
        *(float4*)(&As[r][c4 * 4]) = v;
    }

    float acc[4][4];
    #pragma unroll
    for (int i = 0; i < 4; ++i)
        #pragma unroll
        for (int j = 0; j < 4; ++j)
            acc[i][j] = 0.f;

    for (int ks = 0; ks < 4; ++ks) {
        __syncthreads();             // As staged (ks=0) / prev slice consumed
        for (int i = t; i < 32 * 32; i += 256) {
            int kk = i >> 5, c4 = i & 31;
            *(float4*)(&Ws[kk][c4 * 4]) =
                ((const float4*)(W + (size_t)(ks * 32 + kk) * H_DIM))[c4];
        }
        __syncthreads();

        #pragma unroll 8
        for (int kk = 0; kk < 32; ++kk) {
            float4 w = *(const float4*)(&Ws[kk][tx * 4]);
            int k = ks * 32 + kk;
            #pragma unroll
            for (int i = 0; i < 4; ++i) {
                float a = As[ty * 4 + i][k];
                acc[i][0] += a * w.x;
                acc[i][1] += a * w.y;
                acc[i][2] += a * w.z;
                acc[i][3] += a * w.w;
            }
        }
    }

    float csum[4] = {0.f, 0.f, 0.f, 0.f};
    float csq[4]  = {0.f, 0.f, 0.f, 0.f};

    #pragma unroll
    for (int i = 0; i < 4; ++i) {
        int gr = r0 + ty * 4 + i;
        if (gr < N_NODES) {
            float4 out;
            out.x = acc[i][0]; out.y = acc[i][1];
            out.z = acc[i][2]; out.w = acc[i][3];
            *(float4*)(h + (size_t)gr * H_DIM + tx * 4) = out;
            #pragma unroll
            for (int j = 0; j < 4; ++j) {
                csum[j] += acc[i][j];
                csq[j]  += acc[i][j] * acc[i][j];
            }
        }
    }

    // block-level reduction across ty (stride-9 pad), one plain store/thread
    __syncthreads();
    float* red = &As[0][0];          // needs 256*9 = 2304 floats, 4096 avail
    #pragma unroll
    for (int j = 0; j < 4; ++j) {
        red[(tx * 8 + j) * 9 + ty]     = csum[j];
        red[(tx * 8 + 4 + j) * 9 + ty] = csq[j];
    }
    __syncthreads();
    float s = 0.f;
    #pragma unroll
    for (int q = 0; q < 8; ++q)
        s += red[t * 9 + q];
    partial[(size_t)blockIdx.x * 256 + t] = s;
}

// ---------------------------------------------------------------------------
// K6a: stage-1 partial reduction: 64 blocks sum 1563 rows -> partial2[64][256]
// thread t of block g reads column t of rows g, g+64, ... (coalesced).
// ---------------------------------------------------------------------------
__global__ __launch_bounds__(256) void reduce_partials_kernel(
    const float* __restrict__ partial, float* __restrict__ partial2)
{
    int t = threadIdx.x;
    int g = blockIdx.x;
    float s = 0.f;
    for (int b = g; b < GEMM_GRID; b += RED_NBLK)
        s += partial[(size_t)b * 256 + t];
    partial2[(size_t)g * 256 + t] = s;
}

// ---------------------------------------------------------------------------
// K6b: sum the 64 stage-1 rows (L2-hot, 16 loads/thread), fold BN stats.
// ---------------------------------------------------------------------------
__global__ __launch_bounds__(1024) void bn_stats_kernel(
    const float* __restrict__ partial2,
    const float* __restrict__ gamma,
    const float* __restrict__ beta,
    float* __restrict__ scale,
    float* __restrict__ shift)
{
    __shared__ float tot[4][256];
    __shared__ float tot2[256];
    int v = threadIdx.x & 255;
    int q = threadIdx.x >> 8;
    float s = 0.f;
    for (int b = q; b < RED_NBLK; b += 4)
        s += partial2[(size_t)b * 256 + v];
    tot[q][v] = s;
    __syncthreads();
    if (threadIdx.x < 256)
        tot2[v] = tot[0][v] + tot[1][v] + tot[2][v] + tot[3][v];
    __syncthreads();
    if (threadIdx.x < 128) {
        int c = threadIdx.x;
        int base = (c >> 2) * 8 + (c & 3);
        float cs = tot2[base];
        float cq = tot2[base + 4];
        const float invN = 1.0f / (float)N_NODES;
        float mu  = cs * invN;
        float var = cq * invN - mu * mu;       // biased, matches jnp.var
        float sc  = gamma[c] * rsqrtf(var + BN_EPS);
        scale[c] = sc;
        shift[c] = beta[c] - mu * sc;
    }
}

// ---------------------------------------------------------------------------
// K7: out = tanh(h*scale + shift), in place
// ---------------------------------------------------------------------------
__global__ __launch_bounds__(256) void bn_tanh_kernel(
    float* __restrict__ h,
    const float* __restrict__ scale,
    const float* __restrict__ shift)
{
    size_t i = (size_t)blockIdx.x * blockDim.x + threadIdx.x;
    size_t idx4 = i * 4;
    if (idx4 >= (size_t)N_NODES * H_DIM) return;
    int c = (int)(idx4 & (H_DIM - 1));
    float4 v = *(float4*)(h + idx4);
    v.x = tanhf(v.x * scale[c + 0] + shift[c + 0]);
    v.y = tanhf(v.y * scale[c + 1] + shift[c + 1]);
    v.z = tanhf(v.z * scale[c + 2] + shift[c + 2]);
    v.w = tanhf(v.w * scale[c + 3] + shift[c + 3]);
    *(float4*)(h + idx4) = v;
}

// ---------------------------------------------------------------------------
extern "C" void kernel_launch(void* const* d_in, const int* in_sizes, int n_in,
                              void* d_out, int out_size, void* d_ws, size_t ws_size,
                              hipStream_t stream)
{
    const float* ent_emb = (const float*)d_in[0];
    const float* neigh_w = (const float*)d_in[1];
    const float* gamma   = (const float*)d_in[2];
    const float* beta    = (const float*)d_in[3];
    const int*   src     = (const int*)d_in[4];
    const int*   dst     = (const int*)d_in[5];
    float* out = (float*)d_out;

    char* ws = (char*)d_ws;
    float* neigh    = (float*)ws;                                    // 25.6 MB
    int*   deg      = (int*)(ws + (size_t)N_NODES * H_DIM * 4);      // 50000
    int*   rowptr   = deg + N_NODES;                                 // 50001
    int*   cursor   = rowptr + N_NODES + 1;                          // 50000
    int*   csr_src  = cursor + N_NODES;                              // 500000
    int*   blocksum = csr_src + N_EDGES;                             // 196
    int*   blockoff = blocksum + SCAN_NBLK;                          // 196
    float* partial  = (float*)(blockoff + SCAN_NBLK);                // 1563*256
    float* partial2 = partial + (size_t)GEMM_GRID * 256;             // 64*256
    float* scale    = partial2 + (size_t)RED_NBLK * 256;
    float* shift    = scale + H_DIM;

    hipMemsetAsync(deg, 0, N_NODES * sizeof(int), stream);

    // CSR build (counting sort by dst); hierarchical 3-kernel scan
    hist_kernel<<<(N_EDGES + 255) / 256, 256, 0, stream>>>(dst, deg);
    scan_partial_kernel<<<SCAN_NBLK, 256, 0, stream>>>(deg, blocksum);
    scan_blocksums_kernel<<<1, 256, 0, stream>>>(blocksum, blockoff);
    scan_final_kernel<<<SCAN_NBLK, 256, 0, stream>>>(deg, blockoff, rowptr, cursor);
    csr_scatter_kernel<<<(N_EDGES + 255) / 256, 256, 0, stream>>>(src, dst, cursor, csr_src);

    // fused dot + online softmax + aggregate (one store per lane, no atomics)
    node_aggregate_kernel<<<(N_NODES + 7) / 8, 256, 0, stream>>>(
        ent_emb, rowptr, csr_src, neigh);

    // h = neigh @ W + column partials, then hierarchical BN stats + tanh
    gemm_stats_kernel<<<GEMM_GRID, 256, 0, stream>>>(neigh, neigh_w, out, partial);
    reduce_partials_kernel<<<RED_NBLK, 256, 0, stream>>>(partial, partial2);
    bn_stats_kernel<<<1, 1024, 0, stream>>>(partial2, gamma, beta, scale, shift);
    {
        size_t total4 = (size_t)N_NODES * H_DIM / 4;
        int blocks = (int)((total4 + 255) / 256);
        bn_tanh_kernel<<<blocks, 256, 0, stream>>>(out, scale, shift);
    }
}

// Round 9
// 171.516 us; speedup vs baseline: 1.5181x; 1.0075x over previous
//
#include <hip/hip_runtime.h>
#include <hip/hip_bf16.h>
#include <math.h>

#define N_NODES 50000
#define N_EDGES 500000
#define H_DIM   128
#define BN_EPS  1e-5f
#define GEMM_GRID ((N_NODES + 31) / 32)     // 1563: one 32-row tile per block
#define SCAN_NBLK ((N_NODES + 255) / 256)   // 196
#define RED_NBLK  64                        // stage-1 partial-reduction blocks

// ---------------------------------------------------------------------------
// K1: histogram of dst -> deg[]
// ---------------------------------------------------------------------------
__global__ __launch_bounds__(256) void hist_kernel(
    const int* __restrict__ dst, int* __restrict__ deg)
{
    int e = blockIdx.x * blockDim.x + threadIdx.x;
    if (e < N_EDGES) atomicAdd(&deg[dst[e]], 1);
}

// ---------------------------------------------------------------------------
// K2a: per-block sums of deg (196 blocks x 256)
// ---------------------------------------------------------------------------
__global__ __launch_bounds__(256) void scan_partial_kernel(
    const int* __restrict__ deg, int* __restrict__ blocksum)
{
    __shared__ int red[256];
    int t = threadIdx.x;
    int i = blockIdx.x * 256 + t;
    red[t] = (i < N_NODES) ? deg[i] : 0;
    __syncthreads();
    #pragma unroll
    for (int off = 128; off; off >>= 1) {
        if (t < off) red[t] += red[t + off];
        __syncthreads();
    }
    if (t == 0) blocksum[blockIdx.x] = red[0];
}

// ---------------------------------------------------------------------------
// K2b (merged): every block scans the 196 block sums in LDS (784 B, cheap,
// redundant across blocks) to get its own offset, then does its in-block
// exclusive scan of deg -> rowptr, cursor. Saves one latency-bound dispatch.
// ---------------------------------------------------------------------------
__global__ __launch_bounds__(256) void scan_final_kernel(
    const int* __restrict__ deg, const int* __restrict__ blocksum,
    int* __restrict__ rowptr, int* __restrict__ cursor)
{
    __shared__ int bs[256];
    __shared__ int s[256];
    int t = threadIdx.x;

    bs[t] = (t < SCAN_NBLK) ? blocksum[t] : 0;
    __syncthreads();
    for (int off = 1; off < 256; off <<= 1) {
        int v = (t >= off) ? bs[t - off] : 0;
        __syncthreads();
        bs[t] += v;
        __syncthreads();
    }
    int blockoff = (blockIdx.x == 0) ? 0 : bs[blockIdx.x - 1];

    int i = blockIdx.x * 256 + t;
    int v = (i < N_NODES) ? deg[i] : 0;
    s[t] = v;
    __syncthreads();
    for (int off = 1; off < 256; off <<= 1) {
        int u = (t >= off) ? s[t - off] : 0;
        __syncthreads();
        s[t] += u;
        __syncthreads();
    }
    int excl = s[t] - v + blockoff;
    if (i < N_NODES) {
        rowptr[i] = excl;
        cursor[i] = excl;
        if (i == N_NODES - 1) rowptr[N_NODES] = excl + v;
    }
}

// ---------------------------------------------------------------------------
// K3: scatter src ids into CSR slots (counting sort by dst)
// ---------------------------------------------------------------------------
__global__ __launch_bounds__(256) void csr_scatter_kernel(
    const int* __restrict__ src, const int* __restrict__ dst,
    int* __restrict__ cursor, int* __restrict__ csr_src)
{
    int e = blockIdx.x * blockDim.x + threadIdx.x;
    if (e >= N_EDGES) return;
    int pos = atomicAdd(&cursor[dst[e]], 1);
    csr_src[pos] = src[e];
}

// ---------------------------------------------------------------------------
// K4: per-dst-node fused dot + online softmax + weighted aggregate.
// 32 lanes per node. 8-way edge unroll (8 outstanding 512B gathers, 8
// interleaved shfl chains, one batched rescale per 8 edges) + 4-way + scalar
// tail. Zero atomics, one float4 store per lane.
// ---------------------------------------------------------------------------
__global__ __launch_bounds__(256) void node_aggregate_kernel(
    const float* __restrict__ emb,
    const int* __restrict__ rowptr,
    const int* __restrict__ csr_src,
    float* __restrict__ neigh)
{
    int node = blockIdx.x * 8 + (threadIdx.x >> 5);
    int lane = threadIdx.x & 31;
    if (node >= N_NODES) return;

    int beg = rowptr[node];
    int end = rowptr[node + 1];

    const float4 b = *((const float4*)(emb + (size_t)node * H_DIM) + lane);

    float m = -INFINITY;
    float denom = 0.f;
    float4 acc = {0.f, 0.f, 0.f, 0.f};

    int e = beg;

    for (; e + 8 <= end; e += 8) {
        float4 a[8];
        float  p[8];
        #pragma unroll
        for (int u = 0; u < 8; ++u) {
            int s = csr_src[e + u];
            a[u] = *((const float4*)(emb + (size_t)s * H_DIM) + lane);
        }
        #pragma unroll
        for (int u = 0; u < 8; ++u)
            p[u] = a[u].x * b.x + a[u].y * b.y + a[u].z * b.z + a[u].w * b.w;
        #pragma unroll
        for (int off = 16; off; off >>= 1) {
            #pragma unroll
            for (int u = 0; u < 8; ++u)
                p[u] += __shfl_xor(p[u], off);
        }
        float mn = m;
        #pragma unroll
        for (int u = 0; u < 8; ++u) mn = fmaxf(mn, p[u]);
        float corr = __expf(m - mn);          // first iter: exp(-inf)=0
        float w[8];
        #pragma unroll
        for (int u = 0; u < 8; ++u) w[u] = __expf(p[u] - mn);
        float ws = 0.f;
        #pragma unroll
        for (int u = 0; u < 8; ++u) ws += w[u];
        denom = denom * corr + ws;
        float sx = 0.f, sy = 0.f, sz = 0.f, sw = 0.f;
        #pragma unroll
        for (int u = 0; u < 8; ++u) {
            sx += a[u].x * w[u];
            sy += a[u].y * w[u];
            sz += a[u].z * w[u];
            sw += a[u].w * w[u];
        }
        acc.x = acc.x * corr + sx;
        acc.y = acc.y * corr + sy;
        acc.z = acc.z * corr + sz;
        acc.w = acc.w * corr + sw;
        m = mn;
    }

    if (e + 4 <= end) {
        float4 a[4];
        float  p[4];
        #pragma unroll
        for (int u = 0; u < 4; ++u) {
            int s = csr_src[e + u];
            a[u] = *((const float4*)(emb + (size_t)s * H_DIM) + lane);
        }
        #pragma unroll
        for (int u = 0; u < 4; ++u)
            p[u] = a[u].x * b.x + a[u].y * b.y + a[u].z * b.z + a[u].w * b.w;
        #pragma unroll
        for (int off = 16; off; off >>= 1) {
            #pragma unroll
            for (int u = 0; u < 4; ++u)
                p[u] += __shfl_xor(p[u], off);
        }
        float mn = fmaxf(fmaxf(fmaxf(p[0], p[1]), fmaxf(p[2], p[3])), m);
        float corr = __expf(m - mn);
        float w[4];
        #pragma unroll
        for (int u = 0; u < 4; ++u) w[u] = __expf(p[u] - mn);
        denom = denom * corr + w[0] + w[1] + w[2] + w[3];
        acc.x = acc.x * corr + a[0].x*w[0] + a[1].x*w[1] + a[2].x*w[2] + a[3].x*w[3];
        acc.y = acc.y * corr + a[0].y*w[0] + a[1].y*w[1] + a[2].y*w[2] + a[3].y*w[3];
        acc.z = acc.z * corr + a[0].z*w[0] + a[1].z*w[1] + a[2].z*w[2] + a[3].z*w[3];
        acc.w = acc.w * corr + a[0].w*w[0] + a[1].w*w[1] + a[2].w*w[2] + a[3].w*w[3];
        m = mn;
        e += 4;
    }

    for (; e < end; ++e) {
        int s = csr_src[e];
        float4 a = *((const float4*)(emb + (size_t)s * H_DIM) + lane);
        float p = a.x * b.x + a.y * b.y + a.z * b.z + a.w * b.w;
        #pragma unroll
        for (int off = 16; off; off >>= 1)
            p += __shfl_xor(p, off);
        float mn   = fmaxf(m, p);
        float corr = __expf(m - mn);
        float w    = __expf(p - mn);
        denom = denom * corr + w;
        acc.x = acc.x * corr + a.x * w;
        acc.y = acc.y * corr + a.y * w;
        acc.z = acc.z * corr + a.z * w;
        acc.w = acc.w * corr + a.w * w;
        m = mn;
    }

    float inv = (end > beg) ? (1.0f / denom) : 0.f;
    float4 o = {acc.x * inv, acc.y * inv, acc.z * inv, acc.w * inv};
    *((float4*)(neigh + (size_t)node * H_DIM) + lane) = o;
}

// ---------------------------------------------------------------------------
// K5: h = neigh @ W (fp32), one 32-row tile per block, k-sliced W staging.
// LDS = 32 KB -> 5 blocks/CU. Column partials -> partial[block][256].
// ---------------------------------------------------------------------------
__global__ __launch_bounds__(256) void gemm_stats_kernel(
    const float* __restrict__ neigh,
    const float* __restrict__ W,
    float* __restrict__ h,
    float* __restrict__ partial)
{
    __shared__ float Ws[32][128];    // 16 KB: one k-slice of W
    __shared__ float As[32][128];    // 16 KB: 32-row tile (reused for reduce)

    int t  = threadIdx.x;
    int tx = t & 31;
    int ty = t >> 5;
    int r0 = blockIdx.x * 32;

    const float4 z4 = {0.f, 0.f, 0.f, 0.f};
    for (int i = t; i < 32 * 32; i += 256) {
        int r = i >> 5, c4 = i & 31;
        int gr = r0 + r;
        float4 v = (gr < N_NODES) ? ((const float4*)(neigh + (size_t)gr * H_DIM))[c4] : z4;
        *(float4*)(&As[r][c4 * 4]) = v;
    }

    float acc[4][4];
    #pragma unroll
    for (int i = 0; i < 4; ++i)
        #pragma unroll
        for (int j = 0; j < 4; ++j)
            acc[i][j] = 0.f;

    for (int ks = 0; ks < 4; ++ks) {
        __syncthreads();             // As staged (ks=0) / prev slice consumed
        for (int i = t; i < 32 * 32; i += 256) {
            int kk = i >> 5, c4 = i & 31;
            *(float4*)(&Ws[kk][c4 * 4]) =
                ((const float4*)(W + (size_t)(ks * 32 + kk) * H_DIM))[c4];
        }
        __syncthreads();

        #pragma unroll 8
        for (int kk = 0; kk < 32; ++kk) {
            float4 w = *(const float4*)(&Ws[kk][tx * 4]);
            int k = ks * 32 + kk;
            #pragma unroll
            for (int i = 0; i < 4; ++i) {
                float a = As[ty * 4 + i][k];
                acc[i][0] += a * w.x;
                acc[i][1] += a * w.y;
                acc[i][2] += a * w.z;
                acc[i][3] += a * w.w;
            }
        }
    }

    float csum[4] = {0.f, 0.f, 0.f, 0.f};
    float csq[4]  = {0.f, 0.f, 0.f, 0.f};

    #pragma unroll
    for (int i = 0; i < 4; ++i) {
        int gr = r0 + ty * 4 + i;
        if (gr < N_NODES) {
            float4 out;
            out.x = acc[i][0]; out.y = acc[i][1];
            out.z = acc[i][2]; out.w = acc[i][3];
            *(float4*)(h + (size_t)gr * H_DIM + tx * 4) = out;
            #pragma unroll
            for (int j = 0; j < 4; ++j) {
                csum[j] += acc[i][j];
                csq[j]  += acc[i][j] * acc[i][j];
            }
        }
    }

    // block-level reduction across ty (stride-9 pad), one plain store/thread
    __syncthreads();
    float* red = &As[0][0];          // needs 256*9 = 2304 floats, 4096 avail
    #pragma unroll
    for (int j = 0; j < 4; ++j) {
        red[(tx * 8 + j) * 9 + ty]     = csum[j];
        red[(tx * 8 + 4 + j) * 9 + ty] = csq[j];
    }
    __syncthreads();
    float s = 0.f;
    #pragma unroll
    for (int q = 0; q < 8; ++q)
        s += red[t * 9 + q];
    partial[(size_t)blockIdx.x * 256 + t] = s;
}

// ---------------------------------------------------------------------------
// K6a: stage-1 partial reduction: 64 blocks sum 1563 rows -> partial2[64][256]
// ---------------------------------------------------------------------------
__global__ __launch_bounds__(256) void reduce_partials_kernel(
    const float* __restrict__ partial, float* __restrict__ partial2)
{
    int t = threadIdx.x;
    int g = blockIdx.x;
    float s = 0.f;
    for (int b = g; b < GEMM_GRID; b += RED_NBLK)
        s += partial[(size_t)b * 256 + t];
    partial2[(size_t)g * 256 + t] = s;
}

// ---------------------------------------------------------------------------
// K6b: sum the 64 stage-1 rows (L2-hot), fold BN stats.
// ---------------------------------------------------------------------------
__global__ __launch_bounds__(1024) void bn_stats_kernel(
    const float* __restrict__ partial2,
    const float* __restrict__ gamma,
    const float* __restrict__ beta,
    float* __restrict__ scale,
    float* __restrict__ shift)
{
    __shared__ float tot[4][256];
    __shared__ float tot2[256];
    int v = threadIdx.x & 255;
    int q = threadIdx.x >> 8;
    float s = 0.f;
    for (int b = q; b < RED_NBLK; b += 4)
        s += partial2[(size_t)b * 256 + v];
    tot[q][v] = s;
    __syncthreads();
    if (threadIdx.x < 256)
        tot2[v] = tot[0][v] + tot[1][v] + tot[2][v] + tot[3][v];
    __syncthreads();
    if (threadIdx.x < 128) {
        int c = threadIdx.x;
        int base = (c >> 2) * 8 + (c & 3);
        float cs = tot2[base];
        float cq = tot2[base + 4];
        const float invN = 1.0f / (float)N_NODES;
        float mu  = cs * invN;
        float var = cq * invN - mu * mu;       // biased, matches jnp.var
        float sc  = gamma[c] * rsqrtf(var + BN_EPS);
        scale[c] = sc;
        shift[c] = beta[c] - mu * sc;
    }
}

// ---------------------------------------------------------------------------
// K7: out = tanh(h*scale + shift), in place
// ---------------------------------------------------------------------------
__global__ __launch_bounds__(256) void bn_tanh_kernel(
    float* __restrict__ h,
    const float* __restrict__ scale,
    const float* __restrict__ shift)
{
    size_t i = (size_t)blockIdx.x * blockDim.x + threadIdx.x;
    size_t idx4 = i * 4;
    if (idx4 >= (size_t)N_NODES * H_DIM) return;
    int c = (int)(idx4 & (H_DIM - 1));
    float4 v = *(float4*)(h + idx4);
    v.x = tanhf(v.x * scale[c + 0] + shift[c + 0]);
    v.y = tanhf(v.y * scale[c + 1] + shift[c + 1]);
    v.z = tanhf(v.z * scale[c + 2] + shift[c + 2]);
    v.w = tanhf(v.w * scale[c + 3] + shift[c + 3]);
    *(float4*)(h + idx4) = v;
}

// ---------------------------------------------------------------------------
extern "C" void kernel_launch(void* const* d_in, const int* in_sizes, int n_in,
                              void* d_out, int out_size, void* d_ws, size_t ws_size,
                              hipStream_t stream)
{
    const float* ent_emb = (const float*)d_in[0];
    const float* neigh_w = (const float*)d_in[1];
    const float* gamma   = (const float*)d_in[2];
    const float* beta    = (const float*)d_in[3];
    const int*   src     = (const int*)d_in[4];
    const int*   dst     = (const int*)d_in[5];
    float* out = (float*)d_out;

    char* ws = (char*)d_ws;
    float* neigh    = (float*)ws;                                    // 25.6 MB
    int*   deg      = (int*)(ws + (size_t)N_NODES * H_DIM * 4);      // 50000
    int*   rowptr   = deg + N_NODES;                                 // 50001
    int*   cursor   = rowptr + N_NODES + 1;                          // 50000
    int*   csr_src  = cursor + N_NODES;                              // 500000
    int*   blocksum = csr_src + N_EDGES;                             // 196
    float* partial  = (float*)(blocksum + SCAN_NBLK);                // 1563*256
    float* partial2 = partial + (size_t)GEMM_GRID * 256;             // 64*256
    float* scale    = partial2 + (size_t)RED_NBLK * 256;
    float* shift    = scale + H_DIM;

    hipMemsetAsync(deg, 0, N_NODES * sizeof(int), stream);

    // CSR build (counting sort by dst); 2-kernel hierarchical scan
    hist_kernel<<<(N_EDGES + 255) / 256, 256, 0, stream>>>(dst, deg);
    scan_partial_kernel<<<SCAN_NBLK, 256, 0, stream>>>(deg, blocksum);
    scan_final_kernel<<<SCAN_NBLK, 256, 0, stream>>>(deg, blocksum, rowptr, cursor);
    csr_scatter_kernel<<<(N_EDGES + 255) / 256, 256, 0, stream>>>(src, dst, cursor, csr_src);

    // fused dot + online softmax + aggregate (one store per lane, no atomics)
    node_aggregate_kernel<<<(N_NODES + 7) / 8, 256, 0, stream>>>(
        ent_emb, rowptr, csr_src, neigh);

    // h = neigh @ W + column partials, then hierarchical BN stats + tanh
    gemm_stats_kernel<<<GEMM_GRID, 256, 0, stream>>>(neigh, neigh_w, out, partial);
    reduce_partials_kernel<<<RED_NBLK, 256, 0, stream>>>(partial, partial2);
    bn_stats_kernel<<<1, 1024, 0, stream>>>(partial2, gamma, beta, scale, shift);
    {
        size_t total4 = (size_t)N_NODES * H_DIM / 4;
        int blocks = (int)((total4 + 255) / 256);
        bn_tanh_kernel<<<blocks, 256, 0, stream>>>(out, scale, shift);
    }
}

// Round 11
// 156.447 us; speedup vs baseline: 1.6643x; 1.0963x over previous
//
#include <hip/hip_runtime.h>
#include <hip/hip_bf16.h>
#include <math.h>

#define N_NODES 50000
#define N_EDGES 500000
#define H_DIM   128
#define BN_EPS  1e-5f
#define GEMM_GRID ((N_NODES + 31) / 32)     // 1563: one 32-row tile per block
#define SCAN_NBLK ((N_NODES + 255) / 256)   // 196
#define RED_NBLK  64                        // stage-1 partial-reduction blocks

typedef __attribute__((ext_vector_type(8))) short short8;
typedef __attribute__((ext_vector_type(4))) float floatx4;

__device__ __forceinline__ ushort f2bf(float x)   // fp32 -> bf16 RNE
{
    unsigned u = __float_as_uint(x);
    unsigned r = (u + 0x7FFFu + ((u >> 16) & 1u)) >> 16;
    return (ushort)r;
}

// ---------------------------------------------------------------------------
// K0: W fp32 [k][c] -> bf16 transposed wt[c][k] (once, 16K elems, ~2 us)
// ---------------------------------------------------------------------------
__global__ __launch_bounds__(256) void cvt_w_kernel(
    const float* __restrict__ W, ushort* __restrict__ wt)
{
    int i = blockIdx.x * 256 + threadIdx.x;
    if (i >= H_DIM * H_DIM) return;
    int k = i >> 7, c = i & 127;
    wt[c * 128 + k] = f2bf(W[i]);
}

// ---------------------------------------------------------------------------
// K1: histogram of dst -> deg[]
// ---------------------------------------------------------------------------
__global__ __launch_bounds__(256) void hist_kernel(
    const int* __restrict__ dst, int* __restrict__ deg)
{
    int e = blockIdx.x * blockDim.x + threadIdx.x;
    if (e < N_EDGES) atomicAdd(&deg[dst[e]], 1);
}

// ---------------------------------------------------------------------------
// K2a: per-block sums of deg (196 blocks x 256)
// ---------------------------------------------------------------------------
__global__ __launch_bounds__(256) void scan_partial_kernel(
    const int* __restrict__ deg, int* __restrict__ blocksum)
{
    __shared__ int red[256];
    int t = threadIdx.x;
    int i = blockIdx.x * 256 + t;
    red[t] = (i < N_NODES) ? deg[i] : 0;
    __syncthreads();
    #pragma unroll
    for (int off = 128; off; off >>= 1) {
        if (t < off) red[t] += red[t + off];
        __syncthreads();
    }
    if (t == 0) blocksum[blockIdx.x] = red[0];
}

// ---------------------------------------------------------------------------
// K2b: every block scans the 196 block sums in LDS (redundant, cheap), then
// in-block exclusive scan of deg -> rowptr, cursor.
// ---------------------------------------------------------------------------
__global__ __launch_bounds__(256) void scan_final_kernel(
    const int* __restrict__ deg, const int* __restrict__ blocksum,
    int* __restrict__ rowptr, int* __restrict__ cursor)
{
    __shared__ int bs[256];
    __shared__ int s[256];
    int t = threadIdx.x;

    bs[t] = (t < SCAN_NBLK) ? blocksum[t] : 0;
    __syncthreads();
    for (int off = 1; off < 256; off <<= 1) {
        int v = (t >= off) ? bs[t - off] : 0;
        __syncthreads();
        bs[t] += v;
        __syncthreads();
    }
    int blockoff = (blockIdx.x == 0) ? 0 : bs[blockIdx.x - 1];

    int i = blockIdx.x * 256 + t;
    int v = (i < N_NODES) ? deg[i] : 0;
    s[t] = v;
    __syncthreads();
    for (int off = 1; off < 256; off <<= 1) {
        int u = (t >= off) ? s[t - off] : 0;
        __syncthreads();
        s[t] += u;
        __syncthreads();
    }
    int excl = s[t] - v + blockoff;
    if (i < N_NODES) {
        rowptr[i] = excl;
        cursor[i] = excl;
        if (i == N_NODES - 1) rowptr[N_NODES] = excl + v;
    }
}

// ---------------------------------------------------------------------------
// K3: scatter src ids into CSR slots (counting sort by dst)
// ---------------------------------------------------------------------------
__global__ __launch_bounds__(256) void csr_scatter_kernel(
    const int* __restrict__ src, const int* __restrict__ dst,
    int* __restrict__ cursor, int* __restrict__ csr_src)
{
    int e = blockIdx.x * blockDim.x + threadIdx.x;
    if (e >= N_EDGES) return;
    int pos = atomicAdd(&cursor[dst[e]], 1);
    csr_src[pos] = src[e];
}

// ---------------------------------------------------------------------------
// K4: per-dst-node fused dot + online softmax + weighted aggregate (fp32).
// 32 lanes per node, 8/4-way edge unroll, zero atomics, one store per lane.
// (fp16 variant failed absmax 0.0205 > 0.02 — score rounding; keep fp32.)
// ---------------------------------------------------------------------------
__global__ __launch_bounds__(256) void node_aggregate_kernel(
    const float* __restrict__ emb,
    const int* __restrict__ rowptr,
    const int* __restrict__ csr_src,
    float* __restrict__ neigh)
{
    int node = blockIdx.x * 8 + (threadIdx.x >> 5);
    int lane = threadIdx.x & 31;
    if (node >= N_NODES) return;

    int beg = rowptr[node];
    int end = rowptr[node + 1];

    const float4 b = *((const float4*)(emb + (size_t)node * H_DIM) + lane);

    float m = -INFINITY;
    float denom = 0.f;
    float4 acc = {0.f, 0.f, 0.f, 0.f};

    int e = beg;

    for (; e + 8 <= end; e += 8) {
        float4 a[8];
        float  p[8];
        #pragma unroll
        for (int u = 0; u < 8; ++u) {
            int s = csr_src[e + u];
            a[u] = *((const float4*)(emb + (size_t)s * H_DIM) + lane);
        }
        #pragma unroll
        for (int u = 0; u < 8; ++u)
            p[u] = a[u].x * b.x + a[u].y * b.y + a[u].z * b.z + a[u].w * b.w;
        #pragma unroll
        for (int off = 16; off; off >>= 1) {
            #pragma unroll
            for (int u = 0; u < 8; ++u)
                p[u] += __shfl_xor(p[u], off);
        }
        float mn = m;
        #pragma unroll
        for (int u = 0; u < 8; ++u) mn = fmaxf(mn, p[u]);
        float corr = __expf(m - mn);          // first iter: exp(-inf)=0
        float w[8];
        #pragma unroll
        for (int u = 0; u < 8; ++u) w[u] = __expf(p[u] - mn);
        float ws = 0.f;
        #pragma unroll
        for (int u = 0; u < 8; ++u) ws += w[u];
        denom = denom * corr + ws;
        float sx = 0.f, sy = 0.f, sz = 0.f, sw = 0.f;
        #pragma unroll
        for (int u = 0; u < 8; ++u) {
            sx += a[u].x * w[u];
            sy += a[u].y * w[u];
            sz += a[u].z * w[u];
            sw += a[u].w * w[u];
        }
        acc.x = acc.x * corr + sx;
        acc.y = acc.y * corr + sy;
        acc.z = acc.z * corr + sz;
        acc.w = acc.w * corr + sw;
        m = mn;
    }

    if (e + 4 <= end) {
        float4 a[4];
        float  p[4];
        #pragma unroll
        for (int u = 0; u < 4; ++u) {
            int s = csr_src[e + u];
            a[u] = *((const float4*)(emb + (size_t)s * H_DIM) + lane);
        }
        #pragma unroll
        for (int u = 0; u < 4; ++u)
            p[u] = a[u].x * b.x + a[u].y * b.y + a[u].z * b.z + a[u].w * b.w;
        #pragma unroll
        for (int off = 16; off; off >>= 1) {
            #pragma unroll
            for (int u = 0; u < 4; ++u)
                p[u] += __shfl_xor(p[u], off);
        }
        float mn = fmaxf(fmaxf(fmaxf(p[0], p[1]), fmaxf(p[2], p[3])), m);
        float corr = __expf(m - mn);
        float w[4];
        #pragma unroll
        for (int u = 0; u < 4; ++u) w[u] = __expf(p[u] - mn);
        denom = denom * corr + w[0] + w[1] + w[2] + w[3];
        acc.x = acc.x * corr + a[0].x*w[0] + a[1].x*w[1] + a[2].x*w[2] + a[3].x*w[3];
        acc.y = acc.y * corr + a[0].y*w[0] + a[1].y*w[1] + a[2].y*w[2] + a[3].y*w[3];
        acc.z = acc.z * corr + a[0].z*w[0] + a[1].z*w[1] + a[2].z*w[2] + a[3].z*w[3];
        acc.w = acc.w * corr + a[0].w*w[0] + a[1].w*w[1] + a[2].w*w[2] + a[3].w*w[3];
        m = mn;
        e += 4;
    }

    for (; e < end; ++e) {
        int s = csr_src[e];
        float4 a = *((const float4*)(emb + (size_t)s * H_DIM) + lane);
        float p = a.x * b.x + a.y * b.y + a.z * b.z + a.w * b.w;
        #pragma unroll
        for (int off = 16; off; off >>= 1)
            p += __shfl_xor(p, off);
        float mn   = fmaxf(m, p);
        float corr = __expf(m - mn);
        float w    = __expf(p - mn);
        denom = denom * corr + w;
        acc.x = acc.x * corr + a.x * w;
        acc.y = acc.y * corr + a.y * w;
        acc.z = acc.z * corr + a.z * w;
        acc.w = acc.w * corr + a.w * w;
        m = mn;
    }

    float inv = (end > beg) ? (1.0f / denom) : 0.f;
    float4 o = {acc.x * inv, acc.y * inv, acc.z * inv, acc.w * inv};
    *((float4*)(neigh + (size_t)node * H_DIM) + lane) = o;
}

// ---------------------------------------------------------------------------
// K5: h = neigh @ W via bf16 MFMA (fp32 accumulate). 32x128 tile per block,
// 4 waves: wave w -> rows (w>>1)*16, cols (w&1)*64; 4 col-tiles x 4 k-steps
// of mfma_f32_16x16x32_bf16. A (neigh) converted fp32->bf16 into LDS; W read
// from pre-transposed bf16 wt[c][k]. Both LDS tiles XOR-swizzled
// (granule ^= row&7) to kill the stride-256B 16-way bank conflict.
// C/D layout (m89-verified): col=lane&15, row=(lane>>4)*4+reg.
// A: row=lane&15, k=(lane>>4)*8+j;  B: col=lane&15, k=(lane>>4)*8+j.
// Stats: partial[block][c]=colsum, partial[block][128+c]=colsumsq.
// ---------------------------------------------------------------------------
__global__ __launch_bounds__(256) void gemm_stats_kernel(
    const float* __restrict__ neigh,
    const ushort* __restrict__ wt,
    float* __restrict__ h,
    float* __restrict__ partial)
{
    __shared__ ushort A_s[32 * 128];    // 8 KB  bf16, swizzled
    __shared__ ushort W_s[128 * 128];   // 32 KB bf16 (wt layout), swizzled
    __shared__ float  red_s[128 * 9];   // 4.5 KB col-sum contributors
    __shared__ float  red_q[128 * 9];   // 4.5 KB col-sq contributors

    int t  = threadIdx.x;
    int r0 = blockIdx.x * 32;

    // stage A: 512 granules (granule = 8 bf16 = 16B), 2 per thread
    for (int g = t; g < 32 * 16; g += 256) {
        int r = g >> 4, gc = g & 15;
        int gr = r0 + r;
        float4 x0 = {0.f,0.f,0.f,0.f}, x1 = {0.f,0.f,0.f,0.f};
        if (gr < N_NODES) {
            const float4* p = (const float4*)(neigh + (size_t)gr * H_DIM + gc * 8);
            x0 = p[0]; x1 = p[1];
        }
        ushort v[8] = {f2bf(x0.x), f2bf(x0.y), f2bf(x0.z), f2bf(x0.w),
                       f2bf(x1.x), f2bf(x1.y), f2bf(x1.z), f2bf(x1.w)};
        int idx = r * 128 + ((gc * 8) ^ ((r & 7) << 3));
        *(short8*)&A_s[idx] = *(short8*)v;
    }
    // stage W: 2048 granules, 8 per thread (coalesced 16B reads of wt)
    for (int g = t; g < 128 * 16; g += 256) {
        int c = g >> 4, gk = g & 15;
        short8 v = *(const short8*)(wt + (size_t)c * 128 + gk * 8);
        int idx = c * 128 + ((gk * 8) ^ ((c & 7) << 3));
        *(short8*)&W_s[idx] = v;
    }
    __syncthreads();

    int w    = t >> 6;
    int lane = t & 63;
    int rbase = (w >> 1) * 16;
    int c0    = (w & 1) * 64;
    int l15   = lane & 15;
    int kgrp  = lane >> 4;          // 0..3
    int arow  = rbase + l15;        // tile-local row this lane supplies
    int k0l   = kgrp * 8;

    floatx4 acc[4] = {{0.f,0.f,0.f,0.f},{0.f,0.f,0.f,0.f},
                      {0.f,0.f,0.f,0.f},{0.f,0.f,0.f,0.f}};

    #pragma unroll
    for (int ks = 0; ks < 4; ++ks) {
        int k0 = ks * 32 + k0l;
        short8 af = *(const short8*)&A_s[arow * 128 + (k0 ^ ((arow & 7) << 3))];
        #pragma unroll
        for (int ct = 0; ct < 4; ++ct) {
            int col = c0 + ct * 16 + l15;
            short8 bf = *(const short8*)&W_s[col * 128 + (k0 ^ ((col & 7) << 3))];
            acc[ct] = __builtin_amdgcn_mfma_f32_16x16x32_bf16(af, bf, acc[ct], 0, 0, 0);
        }
    }

    // epilogue: write h + per-thread column partials (padded rows have acc=0)
    int contrib = (w >> 1) * 4 + kgrp;   // 0..7 per column
    #pragma unroll
    for (int ct = 0; ct < 4; ++ct) {
        int col = c0 + ct * 16 + l15;
        float ps = 0.f, pq = 0.f;
        #pragma unroll
        for (int reg = 0; reg < 4; ++reg) {
            float v = acc[ct][reg];
            int gr = r0 + rbase + kgrp * 4 + reg;
            if (gr < N_NODES) h[(size_t)gr * H_DIM + col] = v;
            ps += v;
            pq += v * v;
        }
        red_s[col * 9 + contrib] = ps;
        red_q[col * 9 + contrib] = pq;
    }
    __syncthreads();

    float s = 0.f;
    if (t < 128) {
        #pragma unroll
        for (int q = 0; q < 8; ++q) s += red_s[t * 9 + q];
    } else {
        #pragma unroll
        for (int q = 0; q < 8; ++q) s += red_q[(t - 128) * 9 + q];
    }
    partial[(size_t)blockIdx.x * 256 + t] = s;
}

// ---------------------------------------------------------------------------
// K6a: stage-1 partial reduction: 64 blocks sum 1563 rows -> partial2[64][256]
// ---------------------------------------------------------------------------
__global__ __launch_bounds__(256) void reduce_partials_kernel(
    const float* __restrict__ partial, float* __restrict__ partial2)
{
    int t = threadIdx.x;
    int g = blockIdx.x;
    float s = 0.f;
    for (int b = g; b < GEMM_GRID; b += RED_NBLK)
        s += partial[(size_t)b * 256 + t];
    partial2[(size_t)g * 256 + t] = s;
}

// ---------------------------------------------------------------------------
// K6b: sum the 64 stage-1 rows (L2-hot), fold BN stats.
// Layout: tot2[c] = colsum, tot2[128+c] = colsumsq.
// ---------------------------------------------------------------------------
__global__ __launch_bounds__(1024) void bn_stats_kernel(
    const float* __restrict__ partial2,
    const float* __restrict__ gamma,
    const float* __restrict__ beta,
    float* __restrict__ scale,
    float* __restrict__ shift)
{
    __shared__ float tot[4][256];
    __shared__ float tot2[256];
    int v = threadIdx.x & 255;
    int q = threadIdx.x >> 8;
    float s = 0.f;
    for (int b = q; b < RED_NBLK; b += 4)
        s += partial2[(size_t)b * 256 + v];
    tot[q][v] = s;
    __syncthreads();
    if (threadIdx.x < 256)
        tot2[v] = tot[0][v] + tot[1][v] + tot[2][v] + tot[3][v];
    __syncthreads();
    if (threadIdx.x < 128) {
        int c = threadIdx.x;
        float cs = tot2[c];
        float cq = tot2[c + 128];
        const float invN = 1.0f / (float)N_NODES;
        float mu  = cs * invN;
        float var = cq * invN - mu * mu;       // biased, matches jnp.var
        float sc  = gamma[c] * rsqrtf(var + BN_EPS);
        scale[c] = sc;
        shift[c] = beta[c] - mu * sc;
    }
}

// ---------------------------------------------------------------------------
// K7: out = tanh(h*scale + shift), in place
// ---------------------------------------------------------------------------
__global__ __launch_bounds__(256) void bn_tanh_kernel(
    float* __restrict__ h,
    const float* __restrict__ scale,
    const float* __restrict__ shift)
{
    size_t i = (size_t)blockIdx.x * blockDim.x + threadIdx.x;
    size_t idx4 = i * 4;
    if (idx4 >= (size_t)N_NODES * H_DIM) return;
    int c = (int)(idx4 & (H_DIM - 1));
    float4 v = *(float4*)(h + idx4);
    v.x = tanhf(v.x * scale[c + 0] + shift[c + 0]);
    v.y = tanhf(v.y * scale[c + 1] + shift[c + 1]);
    v.z = tanhf(v.z * scale[c + 2] + shift[c + 2]);
    v.w = tanhf(v.w * scale[c + 3] + shift[c + 3]);
    *(float4*)(h + idx4) = v;
}

// ---------------------------------------------------------------------------
extern "C" void kernel_launch(void* const* d_in, const int* in_sizes, int n_in,
                              void* d_out, int out_size, void* d_ws, size_t ws_size,
                              hipStream_t stream)
{
    const float* ent_emb = (const float*)d_in[0];
    const float* neigh_w = (const float*)d_in[1];
    const float* gamma   = (const float*)d_in[2];
    const float* beta    = (const float*)d_in[3];
    const int*   src     = (const int*)d_in[4];
    const int*   dst     = (const int*)d_in[5];
    float* out = (float*)d_out;

    float*  neigh    = (float*)d_ws;                                 // 25.6 MB
    int*    deg      = (int*)(neigh + (size_t)N_NODES * H_DIM);      // 50000
    int*    rowptr   = deg + N_NODES;                                // 50001
    int*    cursor   = rowptr + N_NODES + 1;                         // 50000
    int*    csr_src  = cursor + N_NODES;                             // 500000
    int*    blocksum = csr_src + N_EDGES;                            // 196
    float*  partial  = (float*)(blocksum + SCAN_NBLK);               // 1563*256
    float*  partial2 = partial + (size_t)GEMM_GRID * 256;            // 64*256
    ushort* wt       = (ushort*)(partial2 + (size_t)RED_NBLK * 256); // 16384
    float*  scale    = (float*)(wt + H_DIM * H_DIM);
    float*  shift    = scale + H_DIM;

    hipMemsetAsync(deg, 0, N_NODES * sizeof(int), stream);

    // W -> bf16 transposed (for MFMA B-fragments)
    cvt_w_kernel<<<(H_DIM * H_DIM + 255) / 256, 256, 0, stream>>>(neigh_w, wt);

    // CSR build (counting sort by dst); 2-kernel hierarchical scan
    hist_kernel<<<(N_EDGES + 255) / 256, 256, 0, stream>>>(dst, deg);
    scan_partial_kernel<<<SCAN_NBLK, 256, 0, stream>>>(deg, blocksum);
    scan_final_kernel<<<SCAN_NBLK, 256, 0, stream>>>(deg, blocksum, rowptr, cursor);
    csr_scatter_kernel<<<(N_EDGES + 255) / 256, 256, 0, stream>>>(src, dst, cursor, csr_src);

    // fused dot + online softmax + aggregate (fp32 gathers, no atomics)
    node_aggregate_kernel<<<(N_NODES + 7) / 8, 256, 0, stream>>>(
        ent_emb, rowptr, csr_src, neigh);

    // h = neigh @ W via bf16 MFMA + column partials, then BN stats + tanh
    gemm_stats_kernel<<<GEMM_GRID, 256, 0, stream>>>(neigh, wt, out, partial);
    reduce_partials_kernel<<<RED_NBLK, 256, 0, stream>>>(partial, partial2);
    bn_stats_kernel<<<1, 1024, 0, stream>>>(partial2, gamma, beta, scale, shift);
    {
        size_t total4 = (size_t)N_NODES * H_DIM / 4;
        int blocks = (int)((total4 + 255) / 256);
        bn_tanh_kernel<<<blocks, 256, 0, stream>>>(out, scale, shift);
    }
}